// Round 11
// baseline (43.755 us; speedup 1.0000x reference)
//
#include <hip/hip_runtime.h>
#include <math.h>

// Multitask loss — R10 math (chunked online softmax, measured best 43.7us)
// + ILP-2 row pairs: all of both rows' loads issued before either compute.
//   loss = mean(bce(pb,tb)) + mean(bce(pt,tt)) + mean(CE(ps,ts))
//        + mean((pb>0)^(pt[:,0]>0)) + mean((pb>0)^(argmax(ps)>0))
// bce(x,y) = max(x,0) - x*y + log1p(exp(-|x|))
//
// Why ILP-2: rocprof rows with L3-resident inputs (FETCH~0) run at the same
// duration as cold rows -> NOT HBM-bound; latency/issue-bound with VGPR=32
// (2-3 loads in flight of 17/row). Pair rows + __launch_bounds__(256,4)
// (VGPR cap 128) so ~58 load values stay in flight across row-A's compute.
// R7's ILP test was invalidated by its atomic-finish tail; this isolates ILP.
//
// Measured dead-ends (do not revisit): LDS staging (R5/R8), single-kernel
// atomic finish (R5/R7), 4-consecutive-rows dwordx4 (R4), quad-cooperative
// shuffles (R6), 8192 blocks (R9).
// Fast intrinsics (__expf/__logf): tolerance 0.117 absmax on ~5.8 scalar.

#define NBLOCKS 2048
#define NTHREADS 256

__device__ __forceinline__ float bce_term(float x, float y) {
    // max(x,0) - x*y + log1p(exp(-|x|)); log arg in (1,2] -> no cancellation
    return fmaxf(x, 0.0f) - x * y + __logf(1.0f + __expf(-fabsf(x)));
}

// Tasks A+B+C+XOR for one row; everything statically indexed after inlining.
__device__ __forceinline__ float row_compute(
    float4 v0, float4 v1, float4 v2, float4 v3,   // ps[r,0:16]
    const float* ptv, const float* ttv,           // pt[r,:], tt[r,:] (local)
    float xb, float yb, int tg)
{
    // task A
    float c = fmaxf(xb, 0.0f) - xb * yb + __logf(1.0f + __expf(-fabsf(xb)));

    // task B (weight 1/5)
    float st = 0.0f;
    #pragma unroll
    for (int j = 0; j < 5; ++j) st += bce_term(ptv[j], ttv[j]);
    c += st * 0.2f;

    // task C: chunked online softmax (low live set)
    float m, se, xt, m15;
    const float x0 = v0.x;
    {
        const float cm_ex0 = fmaxf(fmaxf(v0.y, v0.z), v0.w);
        m15 = cm_ex0;
        m   = fmaxf(v0.x, cm_ex0);
        se  = __expf(v0.x - m) + __expf(v0.y - m) +
              __expf(v0.z - m) + __expf(v0.w - m);
        const int k = tg & 3;
        const float sel = (k == 0) ? v0.x : (k == 1) ? v0.y
                        : (k == 2) ? v0.z : v0.w;
        xt = ((tg >> 2) == 0) ? sel : 0.0f;
    }
    const float4 ch[3] = { v1, v2, v3 };
    #pragma unroll
    for (int q = 0; q < 3; ++q) {
        const float4 v = ch[q];
        const float cm = fmaxf(fmaxf(v.x, v.y), fmaxf(v.z, v.w));
        const float cs = __expf(v.x - cm) + __expf(v.y - cm) +
                         __expf(v.z - cm) + __expf(v.w - cm);
        const float mn = fmaxf(m, cm);
        se = se * __expf(m - mn) + cs * __expf(cm - mn);
        m  = mn;
        m15 = fmaxf(m15, cm);
        const int k = tg & 3;
        const float sel = (k == 0) ? v.x : (k == 1) ? v.y
                        : (k == 2) ? v.z : v.w;
        xt = ((tg >> 2) == (q + 1)) ? sel : xt;
    }
    c += m + __logf(se) - xt;  // -logp[tg]

    // consistency XOR terms
    const bool bc = xb > 0.0f;
    c += (bc != (ptv[0] > 0.0f)) ? 1.0f : 0.0f;
    c += (bc != (m15 > x0)) ? 1.0f : 0.0f;   // argmax>0, strict ties
    return c;
}

__global__ __launch_bounds__(NTHREADS, 4) void mtl_partial_kernel(
    const float* __restrict__ pb,   // [B]    y_pred_binary
    const float* __restrict__ pt,   // [B,5]  y_pred_type
    const float* __restrict__ ps,   // [B,16] y_pred_source
    const float* __restrict__ tb,   // [B]    y_true_binary
    const float* __restrict__ tt,   // [B,5]  y_true_type
    const int*   __restrict__ ts,   // [B]    y_true_source
    double* __restrict__ partial,   // [NBLOCKS]
    int B)
{
    const int S  = NBLOCKS * NTHREADS;
    const int r0 = blockIdx.x * NTHREADS + threadIdx.x;
    float acc = 0.0f;  // 4 rows (~30 max each): f32 exact (absmax 0 all rounds)

    if (B == 4 * S) {
        #pragma unroll
        for (int p = 0; p < 2; ++p) {
            const int ra = r0 + (2 * p) * S;
            const int rb = ra + S;

            // ---- issue ALL loads for both rows before any compute ----
            const float4* Aps = reinterpret_cast<const float4*>(ps + (size_t)ra * 16);
            const float4* Bps = reinterpret_cast<const float4*>(ps + (size_t)rb * 16);
            const float4 a0 = Aps[0], a1 = Aps[1], a2 = Aps[2], a3 = Aps[3];
            const float4 b0 = Bps[0], b1 = Bps[1], b2 = Bps[2], b3 = Bps[3];

            float apt[5], att[5], bpt[5], btt[5];
            #pragma unroll
            for (int j = 0; j < 5; ++j) {
                apt[j] = pt[(size_t)ra * 5 + j];
                att[j] = tt[(size_t)ra * 5 + j];
            }
            #pragma unroll
            for (int j = 0; j < 5; ++j) {
                bpt[j] = pt[(size_t)rb * 5 + j];
                btt[j] = tt[(size_t)rb * 5 + j];
            }
            const float axb = pb[ra], ayb = tb[ra];
            const float bxb = pb[rb], byb = tb[rb];
            const int   atg = ts[ra], btg = ts[rb];

            // ---- compute row A (row B's loads still in flight) ----
            acc += row_compute(a0, a1, a2, a3, apt, att, axb, ayb, atg);
            acc += row_compute(b0, b1, b2, b3, bpt, btt, bxb, byb, btg);
        }
    } else {
        // generic fallback (R10 structure)
        for (int i = r0; i < B; i += S) {
            const float4* ps4 = reinterpret_cast<const float4*>(ps + (size_t)i * 16);
            const float4 v0 = ps4[0], v1 = ps4[1], v2 = ps4[2], v3 = ps4[3];
            float ptv[5], ttv[5];
            #pragma unroll
            for (int j = 0; j < 5; ++j) {
                ptv[j] = pt[(size_t)i * 5 + j];
                ttv[j] = tt[(size_t)i * 5 + j];
            }
            acc += row_compute(v0, v1, v2, v3, ptv, ttv, pb[i], tb[i], ts[i]);
        }
    }

    // ---- block reduction (wave shfl in f32, cross-wave via LDS) ----
    float a = acc;
    #pragma unroll
    for (int off = 32; off > 0; off >>= 1)
        a += __shfl_down(a, off, 64);

    __shared__ double smem[NTHREADS / 64];
    const int lane = threadIdx.x & 63;
    const int wave = threadIdx.x >> 6;
    if (lane == 0) smem[wave] = (double)a;
    __syncthreads();
    if (threadIdx.x == 0) {
        double s = 0.0;
        #pragma unroll
        for (int w = 0; w < NTHREADS / 64; ++w) s += smem[w];
        partial[blockIdx.x] = s;
    }
}

__global__ __launch_bounds__(NTHREADS) void mtl_final_kernel(
    const double* __restrict__ partial, float* __restrict__ out, int nblocks, int B)
{
    double acc = 0.0;
    for (int i = threadIdx.x; i < nblocks; i += NTHREADS)
        acc += partial[i];
    #pragma unroll
    for (int off = 32; off > 0; off >>= 1)
        acc += __shfl_down(acc, off, 64);
    __shared__ double smem[NTHREADS / 64];
    const int lane = threadIdx.x & 63;
    const int wave = threadIdx.x >> 6;
    if (lane == 0) smem[wave] = acc;
    __syncthreads();
    if (threadIdx.x == 0) {
        double s = 0.0;
        #pragma unroll
        for (int w = 0; w < NTHREADS / 64; ++w) s += smem[w];
        out[0] = (float)(s / (double)B);
    }
}

extern "C" void kernel_launch(void* const* d_in, const int* in_sizes, int n_in,
                              void* d_out, int out_size, void* d_ws, size_t ws_size,
                              hipStream_t stream) {
    const float* pb = (const float*)d_in[0];
    const float* pt = (const float*)d_in[1];
    const float* ps = (const float*)d_in[2];
    const float* tb = (const float*)d_in[3];
    const float* tt = (const float*)d_in[4];
    const int*   ts = (const int*)d_in[5];
    float* out = (float*)d_out;
    const int B = in_sizes[0];

    double* partial = (double*)d_ws;  // NBLOCKS doubles = 16 KiB

    mtl_partial_kernel<<<NBLOCKS, NTHREADS, 0, stream>>>(pb, pt, ps, tb, tt, ts, partial, B);
    mtl_final_kernel<<<1, NTHREADS, 0, stream>>>(partial, out, NBLOCKS, B);
}